// Round 7
// baseline (180.534 us; speedup 1.0000x reference)
//
#include <hip/hip_runtime.h>
#include <hip/hip_bf16.h>
#include <stdint.h>
#include <stddef.h>

typedef __bf16 bf16_t;
typedef __attribute__((ext_vector_type(4))) __bf16 bf16x4;
typedef __attribute__((ext_vector_type(8))) __bf16 bf16x8;
typedef __attribute__((ext_vector_type(4))) float floatx4;

#define GLD16(gp, lp) __builtin_amdgcn_global_load_lds(                      \
    (__attribute__((address_space(1))) void*)(gp),                           \
    (__attribute__((address_space(3))) void*)(lp), 16, 0, 0)

// ---------------------------------------------------------------------------
// Fused prep: [0,2048) x f32->bf16 | [2048,2816) transpose_w | [2816,3072) transpose_wo
// Q weights (z==0) pre-scaled by (1/sqrt(64))*log2(e).
// ---------------------------------------------------------------------------
__global__ __launch_bounds__(256) void prep(
    const float* __restrict__ x, const float* __restrict__ Wq,
    const float* __restrict__ Wk, const float* __restrict__ Wv,
    const float* __restrict__ Wo, bf16_t* __restrict__ XB,
    bf16_t* __restrict__ WT, bf16_t* __restrict__ WoT) {
  __shared__ bf16_t t[64][65];
  int bx = blockIdx.x;
  const int tid = threadIdx.x;
  if (bx < 2048) {  // convert x
    const int i = (bx * 256 + tid) * 8;
    const float4 v0 = *(const float4*)(x + i);
    const float4 v1 = *(const float4*)(x + i + 4);
    bf16x8 o = {(bf16_t)v0.x, (bf16_t)v0.y, (bf16_t)v0.z, (bf16_t)v0.w,
                (bf16_t)v1.x, (bf16_t)v1.y, (bf16_t)v1.z, (bf16_t)v1.w};
    *(bf16x8*)(XB + i) = o;
    return;
  }
  bx -= 2048;
  const int g = tid >> 6, l = tid & 63;
  if (bx < 768) {  // Wq/Wk/Wv [16][1024][64] -> WT [3072][1024]
    const int d0 = (bx & 15) * 64, h = (bx >> 4) & 15, z = bx >> 8;
    const float* W = (z == 0) ? Wq : (z == 1) ? Wk : Wv;
    const float scl = (z == 0) ? 0.18033688011112042f : 1.0f;
    const float* src = W + (size_t)h * 65536 + (size_t)d0 * 64;  // [d][hd]
    #pragma unroll
    for (int i = 0; i < 16; ++i) { int r = g * 16 + i; t[r][l] = (bf16_t)(src[(size_t)r * 64 + l] * scl); }
    __syncthreads();
    bf16_t* dst = WT + ((size_t)z * 1024 + h * 64) * 1024 + d0;
    #pragma unroll
    for (int i = 0; i < 16; ++i) { int c = g * 16 + i; dst[(size_t)c * 1024 + l] = t[l][c]; }
  } else {  // Wo [1024][1024] -> WoT
    bx -= 768;
    const int r0 = (bx & 15) * 64, c0 = (bx >> 4) * 64;
    #pragma unroll
    for (int i = 0; i < 16; ++i) { int r = g * 16 + i; t[r][l] = (bf16_t)Wo[(size_t)(r0 + r) * 1024 + c0 + l]; }
    __syncthreads();
    #pragma unroll
    for (int i = 0; i < 16; ++i) { int c = g * 16 + i; WoT[(size_t)(c0 + c) * 1024 + r0 + l] = t[l][c]; }
  }
}

// ---------------------------------------------------------------------------
// GEMM body, BK=64. AMODE 0: A staged via global_load_lds (as before).
// AMODE 1 (out_gemm split tiles): A = (f32(P0[pr]) + f32(AO[row])) * rv
// merged in registers -> bf16 -> ds_write to the SAME swizzled LDS layout.
// pr = (row>>11)*1024 + (row&1023) maps split output rows to partial rows.
// l is PER (row, head): each BK=64 K-step spans exactly one head
// (hh = k0>>6), so rv is recomputed per K-step from l0/l1 [2048][16].
// ---------------------------------------------------------------------------
template <bool BIAS, typename OutT, int AMODE>
__device__ __forceinline__ void gemm_body(
    const bf16_t* __restrict__ A, const bf16_t* __restrict__ Bt,
    OutT* __restrict__ C, const float* __restrict__ bias,
    int K, int lda, int ldb, int ldc, int m0, int n0,
    bf16_t* As, bf16_t* Bs,
    const bf16_t* __restrict__ P0, const float* __restrict__ l0,
    const float* __restrict__ l1) {
  const int tid = threadIdx.x;
  const int lane = tid & 63, w = tid >> 6;
  const int qd = lane >> 4, ln = lane & 15;
  const int wm = (w & 1) * 64, wn = (w >> 1) * 64;

  const floatx4 z4 = {0.f, 0.f, 0.f, 0.f};
  floatx4 acc[4][4];
  #pragma unroll
  for (int i = 0; i < 4; ++i)
    #pragma unroll
    for (int j = 0; j < 4; ++j) acc[i][j] = z4;

  for (int k0 = 0; k0 < K; k0 += 64) {
    #pragma unroll
    for (int i = 0; i < 4; ++i) {
      const int c = tid + i * 256;              // 16B chunk id, 1024 per tile
      const int row = c >> 3;                   // 0..127
      const int sg = (c & 7) ^ (row & 7);       // swizzled slot
      if (AMODE == 0) {
        GLD16(A + (size_t)(m0 + row) * lda + k0 + sg * 8, As + (size_t)(w * 64 + i * 256) * 8);
      } else {
        const int grow = m0 + row;
        const int pr = ((grow >> 11) << 10) | (grow & 1023);
        const int hh = k0 >> 6;                 // head of this K-step
        const float rv = 1.0f / (l0[pr * 16 + hh] + l1[pr * 16 + hh]);
        const bf16x8 p1 = *(const bf16x8*)(A + (size_t)grow * lda + k0 + sg * 8);
        const bf16x8 p0 = *(const bf16x8*)(P0 + (size_t)pr * 1024 + k0 + sg * 8);
        bf16x8 mm;
        #pragma unroll
        for (int jj = 0; jj < 8; ++jj)
          mm[jj] = (bf16_t)(((float)p0[jj] + (float)p1[jj]) * rv);
        *(bf16x8*)(As + (size_t)c * 8) = mm;
      }
      GLD16(Bt + (size_t)(n0 + row) * ldb + k0 + sg * 8, Bs + (size_t)(w * 64 + i * 256) * 8);
    }
    __syncthreads();
    #pragma unroll
    for (int h = 0; h < 2; ++h) {
      bf16x8 af[4], bfr[4];
      #pragma unroll
      for (int t = 0; t < 4; ++t) {
        const int ra = wm + t * 16 + ln;
        const int rb = wn + t * 16 + ln;
        af[t]  = *(const bf16x8*)(As + (size_t)ra * 64 + (((h * 4 + qd) ^ (ra & 7)) * 8));
        bfr[t] = *(const bf16x8*)(Bs + (size_t)rb * 64 + (((h * 4 + qd) ^ (rb & 7)) * 8));
      }
      #pragma unroll
      for (int mt = 0; mt < 4; ++mt)
        #pragma unroll
        for (int nt = 0; nt < 4; ++nt)
          acc[mt][nt] = __builtin_amdgcn_mfma_f32_16x16x32_bf16(af[mt], bfr[nt], acc[mt][nt], 0, 0, 0);
    }
    __syncthreads();
  }

  #pragma unroll
  for (int nt = 0; nt < 4; ++nt) {
    const int col = n0 + wn + nt * 16 + ln;
    const float bv = BIAS ? bias[col] : 0.f;
    #pragma unroll
    for (int mt = 0; mt < 4; ++mt) {
      const int row = m0 + wm + mt * 16 + qd * 4;  // C layout: col=lane&15, row=quad*4+reg
      #pragma unroll
      for (int r = 0; r < 4; ++r)
        C[(size_t)(row + r) * ldc + col] = (OutT)(acc[mt][nt][r] + bv);
    }
  }
}

// Fused projections: blocks [0,512) QK gemm (C1[4096][2048]),
// blocks [512,768) V gemm directly transposed (VT[1024][4096]).
__global__ __launch_bounds__(256) void proj_gemm(
    const bf16_t* __restrict__ XB, const bf16_t* __restrict__ WT,
    bf16_t* __restrict__ C1, bf16_t* __restrict__ VT) {
  __shared__ __align__(16) bf16_t As[128 * 64];
  __shared__ __align__(16) bf16_t Bs[128 * 64];
  int bx = blockIdx.x;
  if (bx < 512) {
    gemm_body<false, bf16_t, 0>(XB, WT, C1, nullptr, 1024, 1024, 1024, 2048,
                                (bx & 31) * 128, (bx >> 5) * 128, As, Bs,
                                nullptr, nullptr, nullptr);
  } else {
    bx -= 512;
    gemm_body<false, bf16_t, 0>(WT + (size_t)2048 * 1024, XB, VT, nullptr,
                                1024, 1024, 1024, 4096,
                                (bx & 7) * 128, (bx >> 3) * 128, As, Bs,
                                nullptr, nullptr, nullptr);
  }
}

// Output projection (+bias) -> f32. Split tiles (rows with t>=1024) merge the
// two flash partials (P0 in dead-WT, P1 at AO's own rows) on the fly.
__global__ __launch_bounds__(256) void out_gemm(
    const bf16_t* __restrict__ AO, const bf16_t* __restrict__ WoT,
    float* __restrict__ C, const float* __restrict__ bias,
    const bf16_t* __restrict__ P0, const float* __restrict__ l0,
    const float* __restrict__ l1) {
  __shared__ __align__(16) bf16_t As[128 * 64];
  __shared__ __align__(16) bf16_t Bs[128 * 64];
  const int m0 = blockIdx.x * 128, n0 = blockIdx.y * 128;
  if ((blockIdx.x >> 3) & 1) {
    gemm_body<true, float, 1>(AO, WoT, C, bias, 1024, 1024, 1024, 1024,
                              m0, n0, As, Bs, P0, l0, l1);
  } else {
    gemm_body<true, float, 0>(AO, WoT, C, bias, 1024, 1024, 1024, 1024,
                              m0, n0, As, Bs, nullptr, nullptr, nullptr);
  }
}

// ---------------------------------------------------------------------------
// Flash attention v10b: SPLIT-K over s-tiles for causal makespan.
//  - q-tiles 0..15: one block (s-tiles 0..qt), normalized write (as before).
//  - q-tiles 16..31: TWO blocks. chunk0 = s-tiles 0..15 (never masked),
//    chunk1 = s-tiles 16..qt (mask at st==qt). Max block length 32 -> 16.
//    No-max softmax => partials merge by pure addition in out_gemm.
//    chunk0 -> P0 (dead WT region) + l0; chunk1 -> AO's own (dead) rows + l1.
//    No atomics, no zeroing, no extra kernel.
//  - v10 BUG FIX: l is per (q, HEAD). l0/l1 are now [2048][16]; flash writes
//    lw[(b*1024+local+r)*16 + h] (per-head disjoint -> no cross-head race),
//    and out_gemm applies 1/(l0+l1) per K-step (one head per BK=64 tile).
//  - Grid 1536 = 48 v-slices x 32 (b,h) groups; bid = v*32+g keeps
//    XCD = bid%8 = g%8 constant per (b,h) (K/V L2-local). v ordered
//    longest-work-first so backfill keeps CUs full.
//  - LDS 40960 B -> 4 blocks/CU; K/V XOR-slot-swizzled (pre-swizzled global
//    source + linear GLD16 dest); Ps 8B-slot swizzle; Q pre-scaled;
//    ones-MFMA row-sum; V-frag preload; s_setprio around MFMA clusters.
// ---------------------------------------------------------------------------
__global__ __launch_bounds__(256, 4) void flash_attn(
    const bf16_t* __restrict__ C1, const bf16_t* __restrict__ VT,
    bf16_t* __restrict__ AO, bf16_t* __restrict__ P0,
    float* __restrict__ l0, float* __restrict__ l1) {
  __shared__ __align__(16) bf16_t Ks[2][64 * 64];  // 16384 B
  __shared__ __align__(16) bf16_t Vs[2][64 * 64];  // 16384 B
  __shared__ __align__(16) bf16_t Ps[4][16 * 64];  //  8192 B  (total 40960)

  const int bid = blockIdx.x;
  const int g = bid & 31;             // (b,h) group; XCD = g & 7
  const int b = g >> 4, h = g & 15;
  const int v = bid >> 5;             // 0..47, work-descending
  int qt, s_lo, cm;                   // cm: 0 single, 1 chunk0, 2 chunk1
  if (v < 16)           { qt = 16 + v; s_lo = 0;  cm = 1; }
  else {
    const int u = v - 16, m = u >> 1;
    if ((u & 1) == 0)   { qt = 15 - m; s_lo = 0;  cm = 0; }
    else                { qt = 31 - m; s_lo = 16; cm = 2; }
  }
  const int s_hi = (cm == 1) ? 15 : qt;

  const int tid = threadIdx.x, lane = tid & 63, w = tid >> 6;
  const int qd = lane >> 4, ln = lane & 15;
  const bf16_t* Qb = C1 + (size_t)b * 2048 * 2048;

  // Q B-frags: lane (qd,ln): col=ln -> q, k=qd*8+j -> d (pre-scaled by SCL)
  bf16x8 qf0, qf1;
  {
    const bf16_t* qp = Qb + (size_t)(qt * 64 + w * 16 + ln) * 2048 + h * 64 + qd * 8;
    qf0 = *(const bf16x8*)qp;
    qf1 = *(const bf16x8*)(qp + 32);
  }
  const floatx4 z4 = {0.f, 0.f, 0.f, 0.f};
  floatx4 oacc[4];  // [t][r]: O[q_local=qd*4+r][hd=t*16+ln]
  #pragma unroll
  for (int t = 0; t < 4; ++t) oacc[t] = z4;
  floatx4 osum = z4;  // osum[r] = sum_s P[q=4qd+r][s], replicated over ln
  const bf16_t one = (bf16_t)1.0f;
  const bf16x8 vone = {one, one, one, one, one, one, one, one};

  const bf16_t* Kg = Qb + 1024 + h * 64;                       // + s*2048 + d
  const bf16_t* Vg = VT + (size_t)(h * 64) * 4096 + b * 2048;  // + hd*4096 + t

  const int r0 = tid >> 3;
  const int g0 = ((tid & 7) ^ (r0 & 7)) * 8;

  auto STAGE = [&](int BUF, int SOFF) {
    GLD16(Kg + (size_t)(SOFF + r0) * 2048 + g0,      &Ks[BUF][w * 512]);
    GLD16(Kg + (size_t)(SOFF + r0 + 32) * 2048 + g0, &Ks[BUF][w * 512 + 2048]);
    GLD16(Vg + (size_t)r0 * 4096 + SOFF + g0,        &Vs[BUF][w * 512]);
    GLD16(Vg + (size_t)(r0 + 32) * 4096 + SOFF + g0, &Vs[BUF][w * 512 + 2048]);
  };

  STAGE(0, s_lo * 64);  // prologue: first tile of this chunk

  const int e2 = (ln & 7) << 1;       // Ps 8B-slot swizzle key
  const int swf = qd ^ (ln & 7);      // K/V frag slot swizzle (row&7 == ln&7)

  for (int st = s_lo; st <= s_hi; ++st) {
    const int bi = st & 1;            // s_lo even -> parity starts at 0
    __syncthreads();                  // drains vmcnt: tile st staged
    if (st < s_hi) STAGE(bi ^ 1, (st + 1) * 64);

    // S^T = K Q^T : lane (qd,ln) gets P[q=ln][s=nt*16+qd*4+r]
    floatx4 sa[4];
    __builtin_amdgcn_s_setprio(1);
    #pragma unroll
    for (int nt = 0; nt < 4; ++nt) {
      const bf16_t* kp = &Ks[bi][(nt * 16 + ln) * 64];
      bf16x8 kf0 = *(const bf16x8*)(kp + swf * 8);
      bf16x8 kf1 = *(const bf16x8*)(kp + (swf ^ 4) * 8);
      floatx4 t0 = z4;
      t0 = __builtin_amdgcn_mfma_f32_16x16x32_bf16(kf0, qf0, t0, 0, 0, 0);
      t0 = __builtin_amdgcn_mfma_f32_16x16x32_bf16(kf1, qf1, t0, 0, 0, 0);
      sa[nt] = t0;
    }
    __builtin_amdgcn_s_setprio(0);

    // V-frag preload (independent of Ps round-trip)
    bf16x8 vf0[4], vf1[4];
    #pragma unroll
    for (int t = 0; t < 4; ++t) {
      const bf16_t* vp = &Vs[bi][(t * 16 + ln) * 64];
      vf0[t] = *(const bf16x8*)(vp + swf * 8);
      vf1[t] = *(const bf16x8*)(vp + (swf ^ 4) * 8);
    }

    // softmax -> Ps (swizzled, wave-private; in-wave DS order)
    #pragma unroll
    for (int nt = 0; nt < 4; ++nt) {
      float p[4];
      #pragma unroll
      for (int r = 0; r < 4; ++r) {
        float v2 = sa[nt][r];
        if (st == qt && (nt * 16 + qd * 4 + r) > (w * 16 + ln)) v2 = -1e30f;
        p[r] = __builtin_amdgcn_exp2f(v2);
      }
      bf16x4 pk = {(bf16_t)p[0], (bf16_t)p[1], (bf16_t)p[2], (bf16_t)p[3]};
      *(bf16x4*)(&Ps[w][ln * 64 + (((nt * 4 + qd) ^ e2) << 2)]) = pk;
    }
    bf16x8 pa0 = *(const bf16x8*)(&Ps[w][ln * 64 + ((((qd << 1)    ) ^ e2) << 2)]);
    bf16x8 pa1 = *(const bf16x8*)(&Ps[w][ln * 64 + ((((qd << 1) + 8) ^ e2) << 2)]);

    // PV: oacc += P * V;  osum += P * 1 (row sums on the MFMA pipe)
    __builtin_amdgcn_s_setprio(1);
    #pragma unroll
    for (int t = 0; t < 4; ++t) {
      oacc[t] = __builtin_amdgcn_mfma_f32_16x16x32_bf16(pa0, vf0[t], oacc[t], 0, 0, 0);
      oacc[t] = __builtin_amdgcn_mfma_f32_16x16x32_bf16(pa1, vf1[t], oacc[t], 0, 0, 0);
    }
    osum = __builtin_amdgcn_mfma_f32_16x16x32_bf16(pa0, vone, osum, 0, 0, 0);
    osum = __builtin_amdgcn_mfma_f32_16x16x32_bf16(pa1, vone, osum, 0, 0, 0);
    __builtin_amdgcn_s_setprio(0);
  }

  if (cm == 0) {
    // single: normalized write (osum[r] holds l(q=4qd+r) in-lane)
    #pragma unroll
    for (int r = 0; r < 4; ++r) {
      const float lr = 1.0f / osum[r];
      #pragma unroll
      for (int t = 0; t < 4; ++t) {
        const int col = h * 64 + t * 16 + ln;
        const int row = b * 2048 + qt * 64 + w * 16 + qd * 4 + r;
        AO[(size_t)row * 1024 + col] = (bf16_t)(oacc[t][r] * lr);
      }
    }
  } else {
    // chunk: unnormalized partial + per-head lsum. chunk0 -> P0/l0,
    // chunk1 -> AO/l1. l arrays are [2048][16] (row, head).
    const int local = (qt - 16) * 64 + w * 16 + qd * 4;  // + r
    bf16_t* Pw = (cm == 1)
        ? P0 + (size_t)(b * 1024 + local) * 1024
        : AO + (size_t)(b * 2048 + qt * 64 + w * 16 + qd * 4) * 1024;
    float* lw = (cm == 1) ? l0 : l1;
    #pragma unroll
    for (int r = 0; r < 4; ++r) {
      #pragma unroll
      for (int t = 0; t < 4; ++t) {
        const int col = h * 64 + t * 16 + ln;
        Pw[(size_t)r * 1024 + col] = (bf16_t)oacc[t][r];
      }
      if (ln == 0) lw[(size_t)(b * 1024 + local + r) * 16 + h] = osum[r];
    }
  }
}

// ---------------------------------------------------------------------------
extern "C" void kernel_launch(void* const* d_in, const int* in_sizes, int n_in,
                              void* d_out, int out_size, void* d_ws, size_t ws_size,
                              hipStream_t stream) {
  const float* x  = (const float*)d_in[0];
  const float* Wq = (const float*)d_in[1];
  const float* Wk = (const float*)d_in[2];
  const float* Wv = (const float*)d_in[3];
  const float* Wo = (const float*)d_in[4];
  const float* bo = (const float*)d_in[5];
  float* out = (float*)d_out;

  // Workspace (33.56 MB, proven safe):
  bf16_t* WT  = (bf16_t*)d_ws;               // [3072][1024] 6.29 MB (dead after proj:
                                             //   reused as P0 [2048][1024] + l0/l1)
  bf16_t* WoT = WT + (size_t)3072 * 1024;    // [1024][1024] 2.10 MB
  bf16_t* C1  = WoT + (size_t)1024 * 1024;   // [4096][2048] 16.78 MB (Q|K cols)
  bf16_t* AO  = C1 + (size_t)4096 * 2048;    // [4096][1024] 8.39 MB (split rows carry
                                             //   chunk1 partials until out_gemm merges)
  // d_out doubles as scratch (16.78 MB; fully overwritten by final gemm):
  bf16_t* XB  = (bf16_t*)d_out;              // [4096][1024] bf16, lower half
  bf16_t* VT  = XB + (size_t)4096 * 1024;    // [1024][4096] bf16, upper half

  bf16_t* P0 = WT;                                   // 2048 rows, 4.19 MB
  float*  l0 = (float*)(WT + (size_t)2048 * 1024);   // [2048][16] 128 KB
  float*  l1 = l0 + (size_t)2048 * 16;               // [2048][16] 128 KB (< WoT)

  prep<<<dim3(3072), 256, 0, stream>>>(x, Wq, Wk, Wv, Wo, XB, WT, WoT);
  proj_gemm<<<dim3(768), 256, 0, stream>>>(XB, WT, C1, VT);
  flash_attn<<<dim3(1536), 256, 0, stream>>>(C1, VT, AO, P0, l0, l1);
  out_gemm<<<dim3(32, 8), 256, 0, stream>>>(AO, WoT, out, bo, P0, l0, l1);
}

// Round 8
// 171.245 us; speedup vs baseline: 1.0542x; 1.0542x over previous
//
#include <hip/hip_runtime.h>
#include <hip/hip_bf16.h>
#include <stdint.h>
#include <stddef.h>

typedef __bf16 bf16_t;
typedef __attribute__((ext_vector_type(4))) __bf16 bf16x4;
typedef __attribute__((ext_vector_type(8))) __bf16 bf16x8;
typedef __attribute__((ext_vector_type(4))) float floatx4;

#define GLD16(gp, lp) __builtin_amdgcn_global_load_lds(                      \
    (__attribute__((address_space(1))) void*)(gp),                           \
    (__attribute__((address_space(3))) void*)(lp), 16, 0, 0)

// ---------------------------------------------------------------------------
// Fused prep: [0,2048) x f32->bf16 | [2048,2816) transpose_w | [2816,3072) transpose_wo
// Q weights (z==0) pre-scaled by (1/sqrt(64))*log2(e).
// ---------------------------------------------------------------------------
__global__ __launch_bounds__(256) void prep(
    const float* __restrict__ x, const float* __restrict__ Wq,
    const float* __restrict__ Wk, const float* __restrict__ Wv,
    const float* __restrict__ Wo, bf16_t* __restrict__ XB,
    bf16_t* __restrict__ WT, bf16_t* __restrict__ WoT) {
  __shared__ bf16_t t[64][65];
  int bx = blockIdx.x;
  const int tid = threadIdx.x;
  if (bx < 2048) {  // convert x
    const int i = (bx * 256 + tid) * 8;
    const float4 v0 = *(const float4*)(x + i);
    const float4 v1 = *(const float4*)(x + i + 4);
    bf16x8 o = {(bf16_t)v0.x, (bf16_t)v0.y, (bf16_t)v0.z, (bf16_t)v0.w,
                (bf16_t)v1.x, (bf16_t)v1.y, (bf16_t)v1.z, (bf16_t)v1.w};
    *(bf16x8*)(XB + i) = o;
    return;
  }
  bx -= 2048;
  const int g = tid >> 6, l = tid & 63;
  if (bx < 768) {  // Wq/Wk/Wv [16][1024][64] -> WT [3072][1024]
    const int d0 = (bx & 15) * 64, h = (bx >> 4) & 15, z = bx >> 8;
    const float* W = (z == 0) ? Wq : (z == 1) ? Wk : Wv;
    const float scl = (z == 0) ? 0.18033688011112042f : 1.0f;
    const float* src = W + (size_t)h * 65536 + (size_t)d0 * 64;  // [d][hd]
    #pragma unroll
    for (int i = 0; i < 16; ++i) { int r = g * 16 + i; t[r][l] = (bf16_t)(src[(size_t)r * 64 + l] * scl); }
    __syncthreads();
    bf16_t* dst = WT + ((size_t)z * 1024 + h * 64) * 1024 + d0;
    #pragma unroll
    for (int i = 0; i < 16; ++i) { int c = g * 16 + i; dst[(size_t)c * 1024 + l] = t[l][c]; }
  } else {  // Wo [1024][1024] -> WoT
    bx -= 768;
    const int r0 = (bx & 15) * 64, c0 = (bx >> 4) * 64;
    #pragma unroll
    for (int i = 0; i < 16; ++i) { int r = g * 16 + i; t[r][l] = (bf16_t)Wo[(size_t)(r0 + r) * 1024 + c0 + l]; }
    __syncthreads();
    #pragma unroll
    for (int i = 0; i < 16; ++i) { int c = g * 16 + i; WoT[(size_t)(c0 + c) * 1024 + r0 + l] = t[l][c]; }
  }
}

// ---------------------------------------------------------------------------
// GEMM body, BK=64 (round-4 form): C[m][n] = sum_k A[m][k]*Bt[n][k] (+bias).
// 128x128 tile, GLD16 async staging, XOR slot swizzle, LDS 32KB -> 4 blk/CU.
// ---------------------------------------------------------------------------
template <bool BIAS, typename OutT>
__device__ __forceinline__ void gemm_body(
    const bf16_t* __restrict__ A, const bf16_t* __restrict__ Bt,
    OutT* __restrict__ C, const float* __restrict__ bias,
    int K, int lda, int ldb, int ldc, int m0, int n0,
    bf16_t* As, bf16_t* Bs) {
  const int tid = threadIdx.x;
  const int lane = tid & 63, w = tid >> 6;
  const int qd = lane >> 4, ln = lane & 15;
  const int wm = (w & 1) * 64, wn = (w >> 1) * 64;

  const floatx4 z4 = {0.f, 0.f, 0.f, 0.f};
  floatx4 acc[4][4];
  #pragma unroll
  for (int i = 0; i < 4; ++i)
    #pragma unroll
    for (int j = 0; j < 4; ++j) acc[i][j] = z4;

  for (int k0 = 0; k0 < K; k0 += 64) {
    #pragma unroll
    for (int i = 0; i < 4; ++i) {
      const int c = tid + i * 256;              // 16B chunk id, 1024 per tile
      const int row = c >> 3;                   // 0..127
      const int sg = (c & 7) ^ (row & 7);       // swizzled slot
      GLD16(A + (size_t)(m0 + row) * lda + k0 + sg * 8, As + (size_t)(w * 64 + i * 256) * 8);
      GLD16(Bt + (size_t)(n0 + row) * ldb + k0 + sg * 8, Bs + (size_t)(w * 64 + i * 256) * 8);
    }
    __syncthreads();
    #pragma unroll
    for (int h = 0; h < 2; ++h) {
      bf16x8 af[4], bfr[4];
      #pragma unroll
      for (int t = 0; t < 4; ++t) {
        const int ra = wm + t * 16 + ln;
        const int rb = wn + t * 16 + ln;
        af[t]  = *(const bf16x8*)(As + (size_t)ra * 64 + (((h * 4 + qd) ^ (ra & 7)) * 8));
        bfr[t] = *(const bf16x8*)(Bs + (size_t)rb * 64 + (((h * 4 + qd) ^ (rb & 7)) * 8));
      }
      #pragma unroll
      for (int mt = 0; mt < 4; ++mt)
        #pragma unroll
        for (int nt = 0; nt < 4; ++nt)
          acc[mt][nt] = __builtin_amdgcn_mfma_f32_16x16x32_bf16(af[mt], bfr[nt], acc[mt][nt], 0, 0, 0);
    }
    __syncthreads();
  }

  #pragma unroll
  for (int nt = 0; nt < 4; ++nt) {
    const int col = n0 + wn + nt * 16 + ln;
    const float bv = BIAS ? bias[col] : 0.f;
    #pragma unroll
    for (int mt = 0; mt < 4; ++mt) {
      const int row = m0 + wm + mt * 16 + qd * 4;  // C layout: col=lane&15, row=quad*4+reg
      #pragma unroll
      for (int r = 0; r < 4; ++r)
        C[(size_t)(row + r) * ldc + col] = (OutT)(acc[mt][nt][r] + bv);
    }
  }
}

// Fused projections: blocks [0,512) QK gemm (C1[4096][2048]),
// blocks [512,768) V gemm directly transposed (VT[1024][4096]).
__global__ __launch_bounds__(256) void proj_gemm(
    const bf16_t* __restrict__ XB, const bf16_t* __restrict__ WT,
    bf16_t* __restrict__ C1, bf16_t* __restrict__ VT) {
  __shared__ __align__(16) bf16_t As[128 * 64];
  __shared__ __align__(16) bf16_t Bs[128 * 64];
  int bx = blockIdx.x;
  if (bx < 512) {
    gemm_body<false, bf16_t>(XB, WT, C1, nullptr, 1024, 1024, 1024, 2048,
                             (bx & 31) * 128, (bx >> 5) * 128, As, Bs);
  } else {
    bx -= 512;
    gemm_body<false, bf16_t>(WT + (size_t)2048 * 1024, XB, VT, nullptr,
                             1024, 1024, 1024, 4096,
                             (bx & 7) * 128, (bx >> 3) * 128, As, Bs);
  }
}

// Output projection (+bias) -> f32 (pure round-4 form, all tiles GLD16).
__global__ __launch_bounds__(256) void out_gemm(
    const bf16_t* __restrict__ AO, const bf16_t* __restrict__ WoT,
    float* __restrict__ C, const float* __restrict__ bias) {
  __shared__ __align__(16) bf16_t As[128 * 64];
  __shared__ __align__(16) bf16_t Bs[128 * 64];
  gemm_body<true, float>(AO, WoT, C, bias, 1024, 1024, 1024, 1024,
                         blockIdx.x * 128, blockIdx.y * 128, As, Bs);
}

// ---------------------------------------------------------------------------
// merge_split: normalize AO's 2048 split rows in place.
// AO[row] = (f32(P0[sr]) + f32(AO[row])) / (l0[sr][h] + l1[sr][h]).
// sr in [0,2048): b = sr>>10, AO row = b*2048 + 1024 + (sr&1023).
// 12.6 MB traffic, fully coalesced bf16x8 -> ~3 us. Keeps out_gemm's A-path
// pure GLD16 (round-7's in-gemm merge lost async staging and cost ~11 us).
// ---------------------------------------------------------------------------
__global__ __launch_bounds__(256) void merge_split(
    const bf16_t* __restrict__ P0, const float* __restrict__ l0,
    const float* __restrict__ l1, bf16_t* __restrict__ AO) {
  const int gid = blockIdx.x * 256 + threadIdx.x;
  const int sr = gid >> 7;            // split row 0..2047
  const int col0 = (gid & 127) * 8;   // 8 cols per thread
  const int h = col0 >> 6;
  const size_t arow = (size_t)((sr >> 10) * 2048 + 1024 + (sr & 1023));
  const float rv = 1.0f / (l0[sr * 16 + h] + l1[sr * 16 + h]);
  const bf16x8 p0 = *(const bf16x8*)(P0 + (size_t)sr * 1024 + col0);
  bf16x8 p1 = *(const bf16x8*)(AO + arow * 1024 + col0);
  #pragma unroll
  for (int j = 0; j < 8; ++j)
    p1[j] = (bf16_t)(((float)p0[j] + (float)p1[j]) * rv);
  *(bf16x8*)(AO + arow * 1024 + col0) = p1;
}

// ---------------------------------------------------------------------------
// Flash attention v10c: SPLIT-K over s-tiles (identical to round-7's v10b,
// which passed correctness). q-tiles 0..15: one block. q-tiles 16..31: two
// blocks (chunk0 = s 0..15 unmasked -> P0/l0; chunk1 = s 16..qt -> AO/l1).
// Max block length 32 -> 16 s-tiles. No-max softmax => partials merge by
// pure addition (merge_split kernel). l0/l1 are per (row, head) [2048][16].
// Grid 1536 = 48 v-slices x 32 (b,h); XCD = bid%8 constant per (b,h);
// v ordered longest-first for backfill. LDS 40960 -> 4 blocks/CU; K/V
// XOR-swizzled via pre-swizzled global src + linear GLD16 dest; Ps 8B-slot
// swizzle; Q pre-scaled; ones-MFMA row-sum; V-frag preload; s_setprio.
// ---------------------------------------------------------------------------
__global__ __launch_bounds__(256, 4) void flash_attn(
    const bf16_t* __restrict__ C1, const bf16_t* __restrict__ VT,
    bf16_t* __restrict__ AO, bf16_t* __restrict__ P0,
    float* __restrict__ l0, float* __restrict__ l1) {
  __shared__ __align__(16) bf16_t Ks[2][64 * 64];  // 16384 B
  __shared__ __align__(16) bf16_t Vs[2][64 * 64];  // 16384 B
  __shared__ __align__(16) bf16_t Ps[4][16 * 64];  //  8192 B  (total 40960)

  const int bid = blockIdx.x;
  const int g = bid & 31;             // (b,h) group; XCD = g & 7
  const int b = g >> 4, h = g & 15;
  const int v = bid >> 5;             // 0..47, work-descending
  int qt, s_lo, cm;                   // cm: 0 single, 1 chunk0, 2 chunk1
  if (v < 16)           { qt = 16 + v; s_lo = 0;  cm = 1; }
  else {
    const int u = v - 16, m = u >> 1;
    if ((u & 1) == 0)   { qt = 15 - m; s_lo = 0;  cm = 0; }
    else                { qt = 31 - m; s_lo = 16; cm = 2; }
  }
  const int s_hi = (cm == 1) ? 15 : qt;

  const int tid = threadIdx.x, lane = tid & 63, w = tid >> 6;
  const int qd = lane >> 4, ln = lane & 15;
  const bf16_t* Qb = C1 + (size_t)b * 2048 * 2048;

  // Q B-frags: lane (qd,ln): col=ln -> q, k=qd*8+j -> d (pre-scaled by SCL)
  bf16x8 qf0, qf1;
  {
    const bf16_t* qp = Qb + (size_t)(qt * 64 + w * 16 + ln) * 2048 + h * 64 + qd * 8;
    qf0 = *(const bf16x8*)qp;
    qf1 = *(const bf16x8*)(qp + 32);
  }
  const floatx4 z4 = {0.f, 0.f, 0.f, 0.f};
  floatx4 oacc[4];  // [t][r]: O[q_local=qd*4+r][hd=t*16+ln]
  #pragma unroll
  for (int t = 0; t < 4; ++t) oacc[t] = z4;
  floatx4 osum = z4;  // osum[r] = sum_s P[q=4qd+r][s], replicated over ln
  const bf16_t one = (bf16_t)1.0f;
  const bf16x8 vone = {one, one, one, one, one, one, one, one};

  const bf16_t* Kg = Qb + 1024 + h * 64;                       // + s*2048 + d
  const bf16_t* Vg = VT + (size_t)(h * 64) * 4096 + b * 2048;  // + hd*4096 + t

  const int r0 = tid >> 3;
  const int g0 = ((tid & 7) ^ (r0 & 7)) * 8;

  auto STAGE = [&](int BUF, int SOFF) {
    GLD16(Kg + (size_t)(SOFF + r0) * 2048 + g0,      &Ks[BUF][w * 512]);
    GLD16(Kg + (size_t)(SOFF + r0 + 32) * 2048 + g0, &Ks[BUF][w * 512 + 2048]);
    GLD16(Vg + (size_t)r0 * 4096 + SOFF + g0,        &Vs[BUF][w * 512]);
    GLD16(Vg + (size_t)(r0 + 32) * 4096 + SOFF + g0, &Vs[BUF][w * 512 + 2048]);
  };

  STAGE(0, s_lo * 64);  // prologue: first tile of this chunk

  const int e2 = (ln & 7) << 1;       // Ps 8B-slot swizzle key
  const int swf = qd ^ (ln & 7);      // K/V frag slot swizzle (row&7 == ln&7)

  for (int st = s_lo; st <= s_hi; ++st) {
    const int bi = st & 1;            // s_lo even -> parity starts at 0
    __syncthreads();                  // drains vmcnt: tile st staged
    if (st < s_hi) STAGE(bi ^ 1, (st + 1) * 64);

    // S^T = K Q^T : lane (qd,ln) gets P[q=ln][s=nt*16+qd*4+r]
    floatx4 sa[4];
    __builtin_amdgcn_s_setprio(1);
    #pragma unroll
    for (int nt = 0; nt < 4; ++nt) {
      const bf16_t* kp = &Ks[bi][(nt * 16 + ln) * 64];
      bf16x8 kf0 = *(const bf16x8*)(kp + swf * 8);
      bf16x8 kf1 = *(const bf16x8*)(kp + (swf ^ 4) * 8);
      floatx4 t0 = z4;
      t0 = __builtin_amdgcn_mfma_f32_16x16x32_bf16(kf0, qf0, t0, 0, 0, 0);
      t0 = __builtin_amdgcn_mfma_f32_16x16x32_bf16(kf1, qf1, t0, 0, 0, 0);
      sa[nt] = t0;
    }
    __builtin_amdgcn_s_setprio(0);

    // V-frag preload (independent of Ps round-trip)
    bf16x8 vf0[4], vf1[4];
    #pragma unroll
    for (int t = 0; t < 4; ++t) {
      const bf16_t* vp = &Vs[bi][(t * 16 + ln) * 64];
      vf0[t] = *(const bf16x8*)(vp + swf * 8);
      vf1[t] = *(const bf16x8*)(vp + (swf ^ 4) * 8);
    }

    // softmax -> Ps (swizzled, wave-private; in-wave DS order)
    #pragma unroll
    for (int nt = 0; nt < 4; ++nt) {
      float p[4];
      #pragma unroll
      for (int r = 0; r < 4; ++r) {
        float v2 = sa[nt][r];
        if (st == qt && (nt * 16 + qd * 4 + r) > (w * 16 + ln)) v2 = -1e30f;
        p[r] = __builtin_amdgcn_exp2f(v2);
      }
      bf16x4 pk = {(bf16_t)p[0], (bf16_t)p[1], (bf16_t)p[2], (bf16_t)p[3]};
      *(bf16x4*)(&Ps[w][ln * 64 + (((nt * 4 + qd) ^ e2) << 2)]) = pk;
    }
    bf16x8 pa0 = *(const bf16x8*)(&Ps[w][ln * 64 + ((((qd << 1)    ) ^ e2) << 2)]);
    bf16x8 pa1 = *(const bf16x8*)(&Ps[w][ln * 64 + ((((qd << 1) + 8) ^ e2) << 2)]);

    // PV: oacc += P * V;  osum += P * 1 (row sums on the MFMA pipe)
    __builtin_amdgcn_s_setprio(1);
    #pragma unroll
    for (int t = 0; t < 4; ++t) {
      oacc[t] = __builtin_amdgcn_mfma_f32_16x16x32_bf16(pa0, vf0[t], oacc[t], 0, 0, 0);
      oacc[t] = __builtin_amdgcn_mfma_f32_16x16x32_bf16(pa1, vf1[t], oacc[t], 0, 0, 0);
    }
    osum = __builtin_amdgcn_mfma_f32_16x16x32_bf16(pa0, vone, osum, 0, 0, 0);
    osum = __builtin_amdgcn_mfma_f32_16x16x32_bf16(pa1, vone, osum, 0, 0, 0);
    __builtin_amdgcn_s_setprio(0);
  }

  if (cm == 0) {
    // single: normalized write (osum[r] holds l(q=4qd+r) in-lane)
    #pragma unroll
    for (int r = 0; r < 4; ++r) {
      const float lr = 1.0f / osum[r];
      #pragma unroll
      for (int t = 0; t < 4; ++t) {
        const int col = h * 64 + t * 16 + ln;
        const int row = b * 2048 + qt * 64 + w * 16 + qd * 4 + r;
        AO[(size_t)row * 1024 + col] = (bf16_t)(oacc[t][r] * lr);
      }
    }
  } else {
    // chunk: unnormalized partial + per-head lsum. chunk0 -> P0/l0,
    // chunk1 -> AO/l1. l arrays are [2048][16] (row, head).
    const int local = (qt - 16) * 64 + w * 16 + qd * 4;  // + r
    bf16_t* Pw = (cm == 1)
        ? P0 + (size_t)(b * 1024 + local) * 1024
        : AO + (size_t)(b * 2048 + qt * 64 + w * 16 + qd * 4) * 1024;
    float* lw = (cm == 1) ? l0 : l1;
    #pragma unroll
    for (int r = 0; r < 4; ++r) {
      #pragma unroll
      for (int t = 0; t < 4; ++t) {
        const int col = h * 64 + t * 16 + ln;
        Pw[(size_t)r * 1024 + col] = (bf16_t)oacc[t][r];
      }
      if (ln == 0) lw[(size_t)(b * 1024 + local + r) * 16 + h] = osum[r];
    }
  }
}

// ---------------------------------------------------------------------------
extern "C" void kernel_launch(void* const* d_in, const int* in_sizes, int n_in,
                              void* d_out, int out_size, void* d_ws, size_t ws_size,
                              hipStream_t stream) {
  const float* x  = (const float*)d_in[0];
  const float* Wq = (const float*)d_in[1];
  const float* Wk = (const float*)d_in[2];
  const float* Wv = (const float*)d_in[3];
  const float* Wo = (const float*)d_in[4];
  const float* bo = (const float*)d_in[5];
  float* out = (float*)d_out;

  // Workspace (33.56 MB, proven safe):
  bf16_t* WT  = (bf16_t*)d_ws;               // [3072][1024] 6.29 MB (dead after proj:
                                             //   reused as P0 [2048][1024] + l0/l1)
  bf16_t* WoT = WT + (size_t)3072 * 1024;    // [1024][1024] 2.10 MB
  bf16_t* C1  = WoT + (size_t)1024 * 1024;   // [4096][2048] 16.78 MB (Q|K cols)
  bf16_t* AO  = C1 + (size_t)4096 * 2048;    // [4096][1024] 8.39 MB (split rows carry
                                             //   chunk1 partials until merge_split)
  // d_out doubles as scratch (16.78 MB; fully overwritten by final gemm):
  bf16_t* XB  = (bf16_t*)d_out;              // [4096][1024] bf16, lower half
  bf16_t* VT  = XB + (size_t)4096 * 1024;    // [1024][4096] bf16, upper half

  bf16_t* P0 = WT;                                   // 2048 rows, 4.19 MB
  float*  l0 = (float*)(WT + (size_t)2048 * 1024);   // [2048][16] 128 KB
  float*  l1 = l0 + (size_t)2048 * 16;               // [2048][16] 128 KB (< WoT)

  prep<<<dim3(3072), 256, 0, stream>>>(x, Wq, Wk, Wv, Wo, XB, WT, WoT);
  proj_gemm<<<dim3(768), 256, 0, stream>>>(XB, WT, C1, VT);
  flash_attn<<<dim3(1536), 256, 0, stream>>>(C1, VT, AO, P0, l0, l1);
  merge_split<<<dim3(1024), 256, 0, stream>>>(P0, l0, l1, AO);
  out_gemm<<<dim3(32, 8), 256, 0, stream>>>(AO, WoT, out, bo);
}